// Round 3
// baseline (88.845 us; speedup 1.0000x reference)
//
#include <hip/hip_runtime.h>

typedef unsigned short ushort_t;
typedef __attribute__((ext_vector_type(8))) short bf16x8;
typedef __attribute__((ext_vector_type(4))) float f32x4;

#define NROWS 4096
#define DIM   256
#define NT    32          // 128-row tiles
#define MARGINF 0.3f

__device__ __forceinline__ ushort_t f2b(float f) {  // fp32 -> bf16 bits, RNE
  unsigned u = __float_as_uint(f);
  u += 0x7fffu + ((u >> 16) & 1u);
  return (ushort_t)(u >> 16);
}

__device__ __forceinline__ void gload_lds16(const void* g, void* l) {
  __builtin_amdgcn_global_load_lds(
      (const __attribute__((address_space(1))) void*)g,
      (__attribute__((address_space(3))) void*)l, 16, 0, 0);
}

// Fused: fp32->bf16 convert + sq-norms. 1024 blocks x 256.
__global__ void k_prep(const float* __restrict__ F, ushort_t* __restrict__ Fb,
                       float* __restrict__ nrm) {
  const int tid = threadIdx.x;
  const int wave = tid >> 6, lane = tid & 63;
  const int row = blockIdx.x * 4 + wave;

  const float4 v = *(const float4*)&F[row * DIM + lane * 4];
  float s = fmaf(v.x, v.x, fmaf(v.y, v.y, fmaf(v.z, v.z, v.w * v.w)));
  #pragma unroll
  for (int off = 32; off; off >>= 1) s += __shfl_down(s, off);
  if (lane == 0) nrm[row] = s;

  ushort4 o;
  o.x = f2b(v.x); o.y = f2b(v.y); o.z = f2b(v.z); o.w = f2b(v.w);
  *(ushort4*)&Fb[row * DIM + lane * 4] = o;
}

// Upper-triangle Gram tiles (128x128, bf16 MFMA), 2-phase overlapped staging,
// fused two-sided batch-hard mining, per-slot partial stores (no atomics).
// grid = 528 blocks (rt<=ct), 256 threads (4 waves as 2x2, each 64x64 = 4x4 frags).
__global__ __launch_bounds__(256, 2) void k_gram(
    const ushort_t* __restrict__ Fb, const int* __restrict__ lab,
    const float* __restrict__ nrm,
    float* __restrict__ pslot, float* __restrict__ nslot) {
  __shared__ alignas(16) ushort_t As[2][128 * 32];   // [row][k] linear, 8KB each
  __shared__ alignas(16) ushort_t Bs[2][128 * 32];
  __shared__ int labi[128], labj[128];
  __shared__ float nrmi[128], nrmj[128];
  __shared__ float redp[2][128], redn[2][128];       // row-side, by wn
  __shared__ float redpc[2][128], rednc[2][128];     // col-side, by wm

  const int tid = threadIdx.x;
  const int wave = tid >> 6, lane = tid & 63;
  const int wm = wave >> 1, wn = wave & 1;

  // triangular decode: block -> (rt, ct), rt <= ct
  int rem = blockIdx.x, rt = 0;
  while (rem >= NT - rt) { rem -= NT - rt; ++rt; }
  const int ct = rt + rem;
  const int row0 = rt * 128, col0 = ct * 128;
  const bool isdiag = (rt == ct);

  if (tid < 128) { labi[tid] = lab[row0 + tid]; nrmi[tid] = nrm[row0 + tid]; }
  else { int t = tid - 128; labj[t] = lab[col0 + t]; nrmj[t] = nrm[col0 + t]; }

  f32x4 acc[4][4];
  #pragma unroll
  for (int m = 0; m < 4; ++m)
    #pragma unroll
    for (int n = 0; n < 4; ++n) acc[m][n] = (f32x4){0.f, 0.f, 0.f, 0.f};

  const int lrow = lane >> 2;        // row within a 16-row staging chunk
  const int lcol = (lane & 3) * 8;   // k offset (ushorts) within the chunk

  // prologue: stage kk=0 into buffer 0
  #pragma unroll
  for (int s = 0; s < 2; ++s) {
    const int rbase = s * 64 + wave * 16;
    gload_lds16(&Fb[(row0 + rbase + lrow) * DIM + lcol], &As[0][rbase * 32]);
    gload_lds16(&Fb[(col0 + rbase + lrow) * DIM + lcol], &Bs[0][rbase * 32]);
  }
  __syncthreads();   // compiler emits vmcnt(0) drain before barrier

  for (int kk = 0; kk < 8; ++kk) {
    const int cur = kk & 1;
    // issue next-tile staging BEFORE compute (overlaps with MFMA below)
    if (kk < 7) {
      const int nxt = cur ^ 1;
      #pragma unroll
      for (int s = 0; s < 2; ++s) {
        const int rbase = s * 64 + wave * 16;
        gload_lds16(&Fb[(row0 + rbase + lrow) * DIM + (kk + 1) * 32 + lcol], &As[nxt][rbase * 32]);
        gload_lds16(&Fb[(col0 + rbase + lrow) * DIM + (kk + 1) * 32 + lcol], &Bs[nxt][rbase * 32]);
      }
    }
    bf16x8 a[4], b[4];
    #pragma unroll
    for (int m = 0; m < 4; ++m)
      a[m] = *(const bf16x8*)&As[cur][(wm * 64 + m * 16 + (lane & 15)) * 32 + (lane >> 4) * 8];
    #pragma unroll
    for (int n = 0; n < 4; ++n)
      b[n] = *(const bf16x8*)&Bs[cur][(wn * 64 + n * 16 + (lane & 15)) * 32 + (lane >> 4) * 8];
    #pragma unroll
    for (int m = 0; m < 4; ++m)
      #pragma unroll
      for (int n = 0; n < 4; ++n)
        acc[m][n] = __builtin_amdgcn_mfma_f32_16x16x32_bf16(a[m], b[n], acc[m][n], 0, 0, 0);
    __syncthreads();   // vmcnt(0): next buffer staged; lgkm/barrier for LDS reuse
  }

  // ---- fused two-sided mining epilogue ----
  // C/D layout: col = lane&15, row = (lane>>4)*4 + reg_idx  [m89/m91]
  const int h = lane >> 4, ccol = lane & 15;
  float posr[4][4], negr[4][4];   // row-side, per (m, j)
  float posc[4], negc[4];         // col-side, per n
  #pragma unroll
  for (int m = 0; m < 4; ++m)
    #pragma unroll
    for (int j = 0; j < 4; ++j) { posr[m][j] = -1e30f; negr[m][j] = 1e30f; }
  #pragma unroll
  for (int n = 0; n < 4; ++n) { posc[n] = -1e30f; negc[n] = 1e30f; }

  #pragma unroll
  for (int m = 0; m < 4; ++m) {
    #pragma unroll
    for (int n = 0; n < 4; ++n) {
      const int cl = wn * 64 + n * 16 + ccol;
      const float nj = nrmj[cl];
      const int lj = labj[cl];
      #pragma unroll
      for (int j = 0; j < 4; ++j) {
        const int rl = wm * 64 + m * 16 + h * 4 + j;
        const float sq = nrmi[rl] + nj - 2.f * acc[m][n][j];
        const bool same = (labi[rl] == lj);
        const bool self = isdiag && (rl == cl);
        if (same) {
          if (!self) {
            posr[m][j] = fmaxf(posr[m][j], sq);
            posc[n] = fmaxf(posc[n], sq);
          }
        } else {
          negr[m][j] = fminf(negr[m][j], sq);
          negc[n] = fminf(negc[n], sq);
        }
      }
    }
  }

  // row-side: reduce across the 16 col-lanes of each h-group
  #pragma unroll
  for (int m = 0; m < 4; ++m) {
    #pragma unroll
    for (int j = 0; j < 4; ++j) {
      float p = posr[m][j], q = negr[m][j];
      #pragma unroll
      for (int mask = 1; mask <= 8; mask <<= 1) {
        p = fmaxf(p, __shfl_xor(p, mask));
        q = fminf(q, __shfl_xor(q, mask));
      }
      if (ccol == 0) {
        const int rl = wm * 64 + m * 16 + h * 4 + j;
        redp[wn][rl] = p; redn[wn][rl] = q;
      }
    }
  }
  // col-side: reduce across the 4 h-groups (lane bits 4-5)
  #pragma unroll
  for (int n = 0; n < 4; ++n) {
    float p = posc[n], q = negc[n];
    #pragma unroll
    for (int mask = 16; mask <= 32; mask <<= 1) {
      p = fmaxf(p, __shfl_xor(p, mask));
      q = fminf(q, __shfl_xor(q, mask));
    }
    if (lane < 16) {
      redpc[wm][wn * 64 + n * 16 + lane] = p;
      rednc[wm][wn * 64 + n * 16 + lane] = q;
    }
  }
  __syncthreads();

  if (tid < 128) {
    // row-side result for row (row0+tid), slot = ct
    const float p = fmaxf(redp[0][tid], redp[1][tid]);
    const float q = fminf(redn[0][tid], redn[1][tid]);
    pslot[ct * NROWS + row0 + tid] = p;
    nslot[ct * NROWS + row0 + tid] = q;
    if (!isdiag) {
      // col-side result for row (col0+tid), slot = rt
      const float pc = fmaxf(redpc[0][tid], redpc[1][tid]);
      const float qc = fminf(rednc[0][tid], rednc[1][tid]);
      pslot[rt * NROWS + col0 + tid] = pc;
      nslot[rt * NROWS + col0 + tid] = qc;
    }
  }
}

// stage 1: 32 blocks x 128 threads; per-row reduce over 32 slots -> block sums
__global__ void k_final1(const float* __restrict__ pslot,
                         const float* __restrict__ nslot,
                         float* __restrict__ bsum, float* __restrict__ bcnt) {
  const int tid = threadIdx.x;
  const int row = blockIdx.x * 128 + tid;
  float p = -1e30f, q = 1e30f;
  #pragma unroll
  for (int s = 0; s < NT; ++s) {
    p = fmaxf(p, pslot[s * NROWS + row]);
    q = fminf(q, nslot[s * NROWS + row]);
  }
  float loss = 0.f, cnt = 0.f;
  if ((p > -1e29f) && (q < 1e29f)) {
    const float hp = sqrtf(fmaxf(p, 1e-12f));
    const float hn = sqrtf(fmaxf(q, 1e-12f));
    loss = fmaxf(hp - hn + MARGINF, 0.f);
    cnt = 1.f;
  }
  const int lane = tid & 63;
  #pragma unroll
  for (int off = 32; off; off >>= 1) {
    loss += __shfl_down(loss, off);
    cnt += __shfl_down(cnt, off);
  }
  __shared__ float ws[2], wc[2];
  if (lane == 0) { ws[tid >> 6] = loss; wc[tid >> 6] = cnt; }
  __syncthreads();
  if (tid == 0) {
    bsum[blockIdx.x] = ws[0] + ws[1];
    bcnt[blockIdx.x] = wc[0] + wc[1];
  }
}

// stage 2: single wave combines 32 block results
__global__ void k_final2(const float* __restrict__ bsum,
                         const float* __restrict__ bcnt,
                         float* __restrict__ out) {
  const int lane = threadIdx.x;
  float s = (lane < NT) ? bsum[lane] : 0.f;
  float c = (lane < NT) ? bcnt[lane] : 0.f;
  #pragma unroll
  for (int off = 32; off; off >>= 1) {
    s += __shfl_down(s, off);
    c += __shfl_down(c, off);
  }
  if (lane == 0) out[0] = (c > 0.f) ? (s / c) : 0.f;
}

extern "C" void kernel_launch(void* const* d_in, const int* in_sizes, int n_in,
                              void* d_out, int out_size, void* d_ws, size_t ws_size,
                              hipStream_t stream) {
  const float* F = (const float*)d_in[0];
  const int* lab = (const int*)d_in[1];
  float* out = (float*)d_out;

  float* pslot = (float*)d_ws;                      // [32][4096]
  float* nslot = pslot + NT * NROWS;                // [32][4096]
  float* nrm = nslot + NT * NROWS;                  // [4096]
  float* bsum = nrm + NROWS;                        // [32]
  float* bcnt = bsum + NT;                          // [32]
  ushort_t* Fb = (ushort_t*)(bcnt + NT);            // [4096*256] bf16

  k_prep<<<NROWS / 4, 256, 0, stream>>>(F, Fb, nrm);
  k_gram<<<NT * (NT + 1) / 2, 256, 0, stream>>>(Fb, lab, nrm, pslot, nslot);
  k_final1<<<NT, 128, 0, stream>>>(pslot, nslot, bsum, bcnt);
  k_final2<<<1, 64, 0, stream>>>(bsum, bcnt, out);
}

// Round 6
// 80.047 us; speedup vs baseline: 1.1099x; 1.1099x over previous
//
#include <hip/hip_runtime.h>

typedef unsigned short ushort_t;
typedef __attribute__((ext_vector_type(8))) short bf16x8;
typedef __attribute__((ext_vector_type(4))) float f32x4;

#define NROWS 4096
#define DIM   256
#define NT    32          // 128-row tiles
#define MARGINF 0.3f

// ---- order-preserving float<->uint encoding for atomic max/min ----
__device__ __forceinline__ unsigned enc_f(float f) {
  unsigned u = __float_as_uint(f);
  return (u & 0x80000000u) ? ~u : (u | 0x80000000u);
}
__device__ __forceinline__ float dec_f(unsigned k) {
  unsigned u = (k & 0x80000000u) ? (k ^ 0x80000000u) : ~k;
  return __uint_as_float(u);
}

__device__ __forceinline__ ushort_t f2b(float f) {  // fp32 -> bf16 bits, RNE
  unsigned u = __float_as_uint(f);
  u += 0x7fffu + ((u >> 16) & 1u);
  return (ushort_t)(u >> 16);
}

__device__ __forceinline__ void gload_lds16(const void* g, void* l) {
  __builtin_amdgcn_global_load_lds(
      (const __attribute__((address_space(1))) void*)g,
      (__attribute__((address_space(3))) void*)l, 16, 0, 0);
}

// Fused: fp32->bf16 convert + sq-norms + posk/negk init. 1024 blocks x 256.
__global__ void k_prep(const float* __restrict__ F, ushort_t* __restrict__ Fb,
                       float* __restrict__ nrm, unsigned* __restrict__ posk,
                       unsigned* __restrict__ negk) {
  const int tid = threadIdx.x;
  const int wave = tid >> 6, lane = tid & 63;
  const int row = blockIdx.x * 4 + wave;

  const float4 v = *(const float4*)&F[row * DIM + lane * 4];
  float s = fmaf(v.x, v.x, fmaf(v.y, v.y, fmaf(v.z, v.z, v.w * v.w)));
  #pragma unroll
  for (int off = 32; off; off >>= 1) s += __shfl_down(s, off);
  if (lane == 0) nrm[row] = s;

  ushort4 o;
  o.x = f2b(v.x); o.y = f2b(v.y); o.z = f2b(v.z); o.w = f2b(v.w);
  *(ushort4*)&Fb[row * DIM + lane * 4] = o;

  const int gid = blockIdx.x * 256 + tid;
  if (gid < NROWS) { posk[gid] = enc_f(-1e30f); negk[gid] = enc_f(1e30f); }
}

// Upper-triangle Gram tiles (128x128, bf16 MFMA), 2-phase overlapped staging,
// fused two-sided batch-hard mining, atomic per-row finalize.
// grid = 528 blocks (rt<=ct); launch_bounds(256,3) -> ALL blocks co-resident.
__global__ __launch_bounds__(256, 3) void k_gram(
    const ushort_t* __restrict__ Fb, const int* __restrict__ lab,
    const float* __restrict__ nrm,
    unsigned* __restrict__ posk, unsigned* __restrict__ negk) {
  __shared__ alignas(16) ushort_t As[2][128 * 32];   // [row][k] linear, 8KB each
  __shared__ alignas(16) ushort_t Bs[2][128 * 32];
  __shared__ int labi[128], labj[128];
  __shared__ float nrmi[128], nrmj[128];
  __shared__ float redp[2][128], redn[2][128];       // row-side, by wn
  __shared__ float redpc[2][128], rednc[2][128];     // col-side, by wm

  const int tid = threadIdx.x;
  const int wave = tid >> 6, lane = tid & 63;
  const int wm = wave >> 1, wn = wave & 1;

  // triangular decode: block -> (rt, ct), rt <= ct
  int rem = blockIdx.x, rt = 0;
  while (rem >= NT - rt) { rem -= NT - rt; ++rt; }
  const int ct = rt + rem;
  const int row0 = rt * 128, col0 = ct * 128;
  const bool isdiag = (rt == ct);

  if (tid < 128) { labi[tid] = lab[row0 + tid]; nrmi[tid] = nrm[row0 + tid]; }
  else { int t = tid - 128; labj[t] = lab[col0 + t]; nrmj[t] = nrm[col0 + t]; }

  f32x4 acc[4][4];
  #pragma unroll
  for (int m = 0; m < 4; ++m)
    #pragma unroll
    for (int n = 0; n < 4; ++n) acc[m][n] = (f32x4){0.f, 0.f, 0.f, 0.f};

  const int lrow = lane >> 2;        // row within a 16-row staging chunk
  const int lcol = (lane & 3) * 8;   // k offset (ushorts) within the chunk

  // prologue: stage kk=0 into buffer 0
  #pragma unroll
  for (int s = 0; s < 2; ++s) {
    const int rbase = s * 64 + wave * 16;
    gload_lds16(&Fb[(row0 + rbase + lrow) * DIM + lcol], &As[0][rbase * 32]);
    gload_lds16(&Fb[(col0 + rbase + lrow) * DIM + lcol], &Bs[0][rbase * 32]);
  }
  __syncthreads();   // compiler emits vmcnt(0) drain before barrier

  for (int kk = 0; kk < 8; ++kk) {
    const int cur = kk & 1;
    // issue next-tile staging BEFORE compute (overlaps with MFMA below)
    if (kk < 7) {
      const int nxt = cur ^ 1;
      #pragma unroll
      for (int s = 0; s < 2; ++s) {
        const int rbase = s * 64 + wave * 16;
        gload_lds16(&Fb[(row0 + rbase + lrow) * DIM + (kk + 1) * 32 + lcol], &As[nxt][rbase * 32]);
        gload_lds16(&Fb[(col0 + rbase + lrow) * DIM + (kk + 1) * 32 + lcol], &Bs[nxt][rbase * 32]);
      }
    }
    bf16x8 a[4], b[4];
    #pragma unroll
    for (int m = 0; m < 4; ++m)
      a[m] = *(const bf16x8*)&As[cur][(wm * 64 + m * 16 + (lane & 15)) * 32 + (lane >> 4) * 8];
    #pragma unroll
    for (int n = 0; n < 4; ++n)
      b[n] = *(const bf16x8*)&Bs[cur][(wn * 64 + n * 16 + (lane & 15)) * 32 + (lane >> 4) * 8];
    #pragma unroll
    for (int m = 0; m < 4; ++m)
      #pragma unroll
      for (int n = 0; n < 4; ++n)
        acc[m][n] = __builtin_amdgcn_mfma_f32_16x16x32_bf16(a[m], b[n], acc[m][n], 0, 0, 0);
    __syncthreads();   // vmcnt(0): next buffer staged; barrier for LDS reuse
  }

  // ---- fused two-sided mining epilogue ----
  // C/D layout: col = lane&15, row = (lane>>4)*4 + reg_idx  [m89/m91]
  const int h = lane >> 4, ccol = lane & 15;
  float posr[4][4], negr[4][4];   // row-side, per (m, j)
  float posc[4], negc[4];         // col-side, per n
  #pragma unroll
  for (int m = 0; m < 4; ++m)
    #pragma unroll
    for (int j = 0; j < 4; ++j) { posr[m][j] = -1e30f; negr[m][j] = 1e30f; }
  #pragma unroll
  for (int n = 0; n < 4; ++n) { posc[n] = -1e30f; negc[n] = 1e30f; }

  #pragma unroll
  for (int m = 0; m < 4; ++m) {
    #pragma unroll
    for (int n = 0; n < 4; ++n) {
      const int cl = wn * 64 + n * 16 + ccol;
      const float nj = nrmj[cl];
      const int lj = labj[cl];
      #pragma unroll
      for (int j = 0; j < 4; ++j) {
        const int rl = wm * 64 + m * 16 + h * 4 + j;
        const float sq = nrmi[rl] + nj - 2.f * acc[m][n][j];
        const bool same = (labi[rl] == lj);
        const bool self = isdiag && (rl == cl);
        if (same) {
          if (!self) {
            posr[m][j] = fmaxf(posr[m][j], sq);
            posc[n] = fmaxf(posc[n], sq);
          }
        } else {
          negr[m][j] = fminf(negr[m][j], sq);
          negc[n] = fminf(negc[n], sq);
        }
      }
    }
  }

  // row-side: reduce across the 16 col-lanes of each h-group
  #pragma unroll
  for (int m = 0; m < 4; ++m) {
    #pragma unroll
    for (int j = 0; j < 4; ++j) {
      float p = posr[m][j], q = negr[m][j];
      #pragma unroll
      for (int mask = 1; mask <= 8; mask <<= 1) {
        p = fmaxf(p, __shfl_xor(p, mask));
        q = fminf(q, __shfl_xor(q, mask));
      }
      if (ccol == 0) {
        const int rl = wm * 64 + m * 16 + h * 4 + j;
        redp[wn][rl] = p; redn[wn][rl] = q;
      }
    }
  }
  // col-side: reduce across the 4 h-groups (lane bits 4-5)
  #pragma unroll
  for (int n = 0; n < 4; ++n) {
    float p = posc[n], q = negc[n];
    #pragma unroll
    for (int mask = 16; mask <= 32; mask <<= 1) {
      p = fmaxf(p, __shfl_xor(p, mask));
      q = fminf(q, __shfl_xor(q, mask));
    }
    if (lane < 16) {
      redpc[wm][wn * 64 + n * 16 + lane] = p;
      rednc[wm][wn * 64 + n * 16 + lane] = q;
    }
  }
  __syncthreads();

  if (tid < 128) {
    // row-side result for row (row0+tid)
    const float p = fmaxf(redp[0][tid], redp[1][tid]);
    const float q = fminf(redn[0][tid], redn[1][tid]);
    atomicMax(&posk[row0 + tid], enc_f(p));
    atomicMin(&negk[row0 + tid], enc_f(q));
    if (!isdiag) {
      // col-side result for row (col0+tid)
      const float pc = fmaxf(redpc[0][tid], redpc[1][tid]);
      const float qc = fminf(rednc[0][tid], rednc[1][tid]);
      atomicMax(&posk[col0 + tid], enc_f(pc));
      atomicMin(&negk[col0 + tid], enc_f(qc));
    }
  }
}

__global__ void k_final(const unsigned* __restrict__ posk,
                        const unsigned* __restrict__ negk,
                        float* __restrict__ out) {
  int t = threadIdx.x;  // 1024 threads
  float sum = 0.f;
  int cnt = 0;
  for (int i = t; i < NROWS; i += 1024) {
    float ps = dec_f(posk[i]);
    float ns = dec_f(negk[i]);
    if ((ps > -1e29f) && (ns < 1e29f)) {
      float hp = sqrtf(fmaxf(ps, 1e-12f));
      float hn = sqrtf(fmaxf(ns, 1e-12f));
      sum += fmaxf(hp - hn + MARGINF, 0.f);
      cnt += 1;
    }
  }
  #pragma unroll
  for (int off = 32; off; off >>= 1) {
    sum += __shfl_down(sum, off);
    cnt += __shfl_down(cnt, off);
  }
  __shared__ float wsum[16];
  __shared__ int wcnt[16];
  int w = t >> 6;
  if ((t & 63) == 0) { wsum[w] = sum; wcnt[w] = cnt; }
  __syncthreads();
  if (t == 0) {
    float S = 0.f; int C = 0;
    #pragma unroll
    for (int i = 0; i < 16; ++i) { S += wsum[i]; C += wcnt[i]; }
    out[0] = (C > 0) ? (S / (float)C) : 0.f;
  }
}

extern "C" void kernel_launch(void* const* d_in, const int* in_sizes, int n_in,
                              void* d_out, int out_size, void* d_ws, size_t ws_size,
                              hipStream_t stream) {
  const float* F = (const float*)d_in[0];
  const int* lab = (const int*)d_in[1];
  float* out = (float*)d_out;

  unsigned* posk = (unsigned*)d_ws;                 // [4096]
  unsigned* negk = posk + NROWS;                    // [4096]
  float* nrm = (float*)(negk + NROWS);              // [4096]
  ushort_t* Fb = (ushort_t*)(nrm + NROWS);          // [4096*256] bf16

  k_prep<<<NROWS / 4, 256, 0, stream>>>(F, Fb, nrm, posk, negk);
  k_gram<<<NT * (NT + 1) / 2, 256, 0, stream>>>(Fb, lab, nrm, posk, negk);
  k_final<<<1, 1024, 0, stream>>>(posk, negk, out);
}